// Round 15
// baseline (532.982 us; speedup 1.0000x reference)
//
#include <hip/hip_runtime.h>
#include <math.h>

#define N_PTS 4096
#define BATCH 4
#define KNB 20

typedef __attribute__((ext_vector_type(8))) short short8v;   // 8 bf16
typedef __attribute__((ext_vector_type(4))) float f32x4;

__device__ __forceinline__ float lrelu(float v){ return fmaxf(v, 0.2f*v); }
__device__ __forceinline__ unsigned fenc(float f){ unsigned u=__float_as_uint(f); return (u&0x80000000u)?~u:(u|0x80000000u); }
__device__ __forceinline__ float fdec(unsigned k){ return (k&0x80000000u)?__uint_as_float(k&0x7fffffffu):__uint_as_float(~k); }

// split f32 -> packed (bf16_hi << 16) | bf16_lo,  v ~= hi + lo, err ~2^-18 rel
__device__ __forceinline__ unsigned pack2(float v){
  unsigned u = __float_as_uint(v);
  unsigned hi = (u + 0x7fffu + ((u>>16)&1u)) >> 16;
  float hf = __uint_as_float(hi<<16);
  unsigned u2 = __float_as_uint(v - hf);
  unsigned lo = (u2 + 0x7fffu + ((u2>>16)&1u)) >> 16;
  return (hi<<16) | lo;
}
__device__ __forceinline__ void cvt8(uint4 v0, uint4 v1, short8v& h, short8v& l){
  unsigned a0=v0.x,a1=v0.y,a2=v0.z,a3=v0.w,a4=v1.x,a5=v1.y,a6=v1.z,a7=v1.w;
  h[0]=(short)(a0>>16); l[0]=(short)(a0&0xffffu);
  h[1]=(short)(a1>>16); l[1]=(short)(a1&0xffffu);
  h[2]=(short)(a2>>16); l[2]=(short)(a2&0xffffu);
  h[3]=(short)(a3>>16); l[3]=(short)(a3&0xffffu);
  h[4]=(short)(a4>>16); l[4]=(short)(a4&0xffffu);
  h[5]=(short)(a5>>16); l[5]=(short)(a5&0xffffu);
  h[6]=(short)(a6>>16); l[6]=(short)(a6&0xffffu);
  h[7]=(short)(a7>>16); l[7]=(short)(a7&0xffffu);
}

// ---- prep device bodies (byte-identical math to the proven standalone kernels) ----
__device__ __forceinline__ void d_scale_rows(int blk, int tid, const float* W, const float* bn,
                                             float* Wf, float* bias, int O, int C){
  int i = blk*256 + tid;
  if (i >= O*C) return;
  int o = i / C;
  float s = bn[o] / sqrtf(bn[3*O+o] + 1e-5f);
  Wf[i] = W[i]*s;
  if (i % C == 0) bias[o] = bn[O+o] - s*bn[2*O+o];
}

__device__ __forceinline__ void d_pack_w(int blk, int tid, const float* W, int ldw, int c0,
                                         const float* bn, int O, int C, int Opad,
                                         unsigned* out, float* bias){
  int i = blk*256 + tid;
  if (i >= Opad*C) return;
  int o = i / C, c = i - o*C;
  float v = 0.f;
  if (o < O){
    float s = 1.f;
    if (bn != nullptr){
      s = bn[o] / sqrtf(bn[3*O+o] + 1e-5f);
      if (bias != nullptr && c == 0) bias[o] = bn[O+o] - s*bn[2*O+o];
    }
    v = W[o*ldw + c0 + c] * s;
  }
  out[i] = pack2(v);
}

// transposed float4-chunk layout: dst[(c/4)*256 + o*4 + c%4], O=64 fixed; 16 blocks x 256 thr
__device__ __forceinline__ void d_build_T4(int blk, int tid, const float* W, int ldw,
                                           const float* bn, float* dst, float* bias,
                                           int c0, int diffoff, int Csrc){
  int o = tid & 63, c = blk*4 + (tid>>6);
  float s = bn[o] / sqrtf(bn[192+o] + 1e-5f);
  float val = 0.f;
  if (c < Csrc){
    val = W[o*ldw + c0 + c];
    if (diffoff) val = W[o*ldw + c0 + diffoff + c] - val;
    val *= s;
  }
  dst[(c>>2)*256 + o*4 + (c&3)] = val;
  if (bias != nullptr && c==0) bias[o] = bn[64+o] - s*bn[128+o];
}

// U1[b][k][o]; 20 blocks x 256 thr (4 waves = 4 flat (k,b) slots each)
__device__ __forceinline__ void d_build_U1(int blk, int tid, const float* x, const float* W1,
                                           const float* bn, float* U1){
  int w = tid>>6, o = tid&63;
  int flat = blk*4 + w;           // 0..79
  int k = flat >> 2, b = flat & 3;
  float s = bn[o] / sqrtf(bn[192+o] + 1e-5f);
  float acc = 0.f;
  #pragma unroll
  for (int c=0;c<6;c++) acc += W1[o*12+c] * x[(b*6+c)*N_PTS + k];
  U1[(b*KNB+k)*64 + o] = acc*s;
}

// V1[pt][o]; 4096 blocks x 256 thr
__device__ __forceinline__ void d_v1(int blk, int tid, const float* x, const float* W1,
                                     const float* bn, float* V1){
  int o = tid&63;
  int pt = blk*4 + (tid>>6);
  int b = pt>>12, n = pt&4095;
  float s = bn[o] / sqrtf(bn[192+o] + 1e-5f);
  float acc = bn[64+o] - s*bn[128+o];
  #pragma unroll
  for (int c=0;c<6;c++)
    acc += s*(W1[o*12+6+c]-W1[o*12+c]) * x[(b*6+c)*N_PTS + n];
  V1[(size_t)pt*64 + o] = acc;
}

// ---- single merged prep kernel: block-range dispatch over 14 independent sub-tasks ----
// segs: 2432 scale7 | 16 pk2 | 16 pk4 | 768 pk6 | 384 pk7 | 512 pk8 | 128 pk9 |
//       16 T4(3L) | 16 T4(3Rd) | 16 T4(5L) | 16 T4(5Rd) | 20 U1 | 4096 V1 | 16 initg = 8452
__global__ __launch_bounds__(256) void k_prep(
    const float* __restrict__ x,  const float* __restrict__ W1,
    const float* __restrict__ W2, const float* __restrict__ W3,
    const float* __restrict__ W4, const float* __restrict__ W5,
    const float* __restrict__ W6, const float* __restrict__ W7,
    const float* __restrict__ W8, const float* __restrict__ W9,
    const float* __restrict__ bn1, const float* __restrict__ bn2,
    const float* __restrict__ bn3, const float* __restrict__ bn4,
    const float* __restrict__ bn5, const float* __restrict__ bn6,
    const float* __restrict__ bn7, const float* __restrict__ bn8,
    float* Wf7, float* bf7,
    unsigned* Wb2p, float* bf2, unsigned* Wb4p, float* bf4,
    unsigned* Wb6p, float* bf6, unsigned* Wb7p,
    unsigned* Wb8p, float* bf8, unsigned* Wb9p,
    float* W3LT4, float* bf3, float* W3RdT4,
    float* W5LT4, float* bf5, float* W5RdT4,
    float* U1, float* V1, unsigned* genc){
  int blk = blockIdx.x, tid = threadIdx.x;
  if (blk < 2432){ d_scale_rows(blk, tid, W7, bn7, Wf7, bf7, 512, 1216); return; }
  blk -= 2432;
  if (blk < 16){ d_pack_w(blk, tid, W2, 64, 0, bn2, 64, 64, 64, Wb2p, bf2); return; }
  blk -= 16;
  if (blk < 16){ d_pack_w(blk, tid, W4, 64, 0, bn4, 64, 64, 64, Wb4p, bf4); return; }
  blk -= 16;
  if (blk < 768){ d_pack_w(blk, tid, W6, 192, 0, bn6, 1024, 192, 1024, Wb6p, bf6); return; }
  blk -= 768;
  if (blk < 384){ d_pack_w(blk, tid, W7, 1216, 1024, bn7, 512, 192, 512, Wb7p, nullptr); return; }
  blk -= 384;
  if (blk < 512){ d_pack_w(blk, tid, W8, 512, 0, bn8, 256, 512, 256, Wb8p, bf8); return; }
  blk -= 512;
  if (blk < 128){ d_pack_w(blk, tid, W9, 256, 0, nullptr, 13, 256, 128, Wb9p, nullptr); return; }
  blk -= 128;
  if (blk < 16){ d_build_T4(blk, tid, W3, 128, bn3, W3LT4, bf3, 0, 0, 64); return; }
  blk -= 16;
  if (blk < 16){ d_build_T4(blk, tid, W3, 128, bn3, W3RdT4, nullptr, 0, 64, 64); return; }
  blk -= 16;
  if (blk < 16){ d_build_T4(blk, tid, W5, 128, bn5, W5LT4, bf5, 0, 0, 64); return; }
  blk -= 16;
  if (blk < 16){ d_build_T4(blk, tid, W5, 128, bn5, W5RdT4, nullptr, 0, 64, 64); return; }
  blk -= 16;
  if (blk < 20){ d_build_U1(blk, tid, x, W1, bn1, U1); return; }
  blk -= 20;
  if (blk < 4096){ d_v1(blk, tid, x, W1, bn1, V1); return; }
  blk -= 4096;
  genc[blk*256 + tid] = fenc(-INFINITY);
}

// ---- U/V precompute ----
__global__ __launch_bounds__(256) void k_uv(const float* __restrict__ xt, const float* __restrict__ WL,
    const float* __restrict__ WRd, const float* __restrict__ bf,
    float* __restrict__ Ut, float* __restrict__ Vt){
  __shared__ float xs[4][64];
  int wid = threadIdx.x>>6, lane = threadIdx.x&63;
  int pt = blockIdx.x*4 + wid;
  xs[wid][lane] = xt[(size_t)pt*64 + lane];
  __syncthreads();
  float U = 0.f, V = bf[lane];
  #pragma unroll
  for (int cb=0;cb<16;cb++){
    float4 wl = ((const float4*)WL)[cb*64+lane];
    float4 wr = ((const float4*)WRd)[cb*64+lane];
    float4 xv = *(const float4*)&xs[wid][cb*4];
    U=fmaf(wl.x,xv.x,U); U=fmaf(wl.y,xv.y,U); U=fmaf(wl.z,xv.z,U); U=fmaf(wl.w,xv.w,U);
    V=fmaf(wr.x,xv.x,V); V=fmaf(wr.y,xv.y,V); V=fmaf(wr.z,xv.z,V); V=fmaf(wr.w,xv.w,V);
  }
  Ut[(size_t)pt*64 + lane] = U;
  Vt[(size_t)pt*64 + lane] = V;
}

// ---- unified MFMA edge-conv: for each point, D[pt][o] = max_k conv(lrelu(U[m_k]+V[pt])) ----
template<int GATHER>
__global__ __launch_bounds__(256) void k_edgemm(const float* __restrict__ Ut,
    const float* __restrict__ Vt, const int* __restrict__ idx,
    const unsigned* __restrict__ Wp, const float* __restrict__ bf,
    float* __restrict__ xout, unsigned* __restrict__ Xb, int coff,
    float* __restrict__ xxout){
  __shared__ short Hh[2][64][72];
  __shared__ short Hl[2][64][72];
  int tid = threadIdx.x;
  int b = blockIdx.z, p0 = blockIdx.x*64;
  int w = tid>>6, lane = tid&63, r15 = lane&15, rb = lane>>4;
  int ptl = tid>>2, c0 = (tid&3)*16;
  size_t ptg = ((size_t)b<<12) + p0 + ptl;
  float v[16];
  #pragma unroll
  for (int q=0;q<4;q++){
    float4 t = *(const float4*)&Vt[ptg*64 + c0 + q*4];
    v[q*4+0]=t.x; v[q*4+1]=t.y; v[q*4+2]=t.z; v[q*4+3]=t.w;
  }
  int mr[KNB];
  if (GATHER){
    const int4* ip4 = (const int4*)(idx + ptg*KNB);
    #pragma unroll
    for (int q=0;q<5;q++){ int4 t=ip4[q]; mr[q*4+0]=t.x; mr[q*4+1]=t.y; mr[q*4+2]=t.z; mr[q*4+3]=t.w; }
  }
  short8v wh[4][2], wl[4][2];
  #pragma unroll
  for (int oi=0;oi<4;oi++)
    #pragma unroll
    for (int ks=0;ks<2;ks++){
      const unsigned* pw = Wp + (size_t)(oi*16+r15)*64 + ks*32 + rb*8;
      uint4 w0 = *(const uint4*)pw, w1 = *(const uint4*)(pw+4);
      cvt8(w0,w1,wh[oi][ks],wl[oi][ks]);
    }
  f32x4 rmax[4];
  #pragma unroll
  for (int oi=0;oi<4;oi++) rmax[oi]=(f32x4){-INFINITY,-INFINITY,-INFINITY,-INFINITY};
  float uc[16], un[16];
  {
    const float* ur = GATHER ? (Ut + ((((size_t)b)<<12) + mr[0])*64 + c0)
                             : (Ut + ((size_t)b*KNB + 0)*64 + c0);
    #pragma unroll
    for (int q=0;q<4;q++){
      float4 t = *(const float4*)(ur + q*4);
      uc[q*4+0]=t.x; uc[q*4+1]=t.y; uc[q*4+2]=t.z; uc[q*4+3]=t.w;
    }
  }
  for (int k=0;k<KNB;k++){
    int buf = k&1;
    #pragma unroll
    for (int q=0;q<2;q++){
      short8v hh, hl;
      #pragma unroll
      for (int e=0;e<8;e++){
        unsigned pk = pack2(lrelu(uc[q*8+e] + v[q*8+e]));
        hh[e]=(short)(pk>>16); hl[e]=(short)(pk&0xffffu);
      }
      *(short8v*)&Hh[buf][ptl][c0+q*8] = hh;
      *(short8v*)&Hl[buf][ptl][c0+q*8] = hl;
    }
    if (k+1 < KNB){
      const float* ur = GATHER ? (Ut + ((((size_t)b)<<12) + mr[k+1])*64 + c0)
                               : (Ut + ((size_t)b*KNB + (k+1))*64 + c0);
      #pragma unroll
      for (int q=0;q<4;q++){
        float4 t = *(const float4*)(ur + q*4);
        un[q*4+0]=t.x; un[q*4+1]=t.y; un[q*4+2]=t.z; un[q*4+3]=t.w;
      }
    }
    __syncthreads();
    f32x4 acc[4];
    #pragma unroll
    for (int oi=0;oi<4;oi++) acc[oi]=(f32x4){0.f,0.f,0.f,0.f};
    #pragma unroll
    for (int ks=0;ks<2;ks++){
      short8v ah = *(const short8v*)&Hh[buf][w*16+r15][ks*32+rb*8];
      short8v al = *(const short8v*)&Hl[buf][w*16+r15][ks*32+rb*8];
      #pragma unroll
      for (int oi=0;oi<4;oi++){
        acc[oi] = __builtin_amdgcn_mfma_f32_16x16x32_bf16(ah, wh[oi][ks], acc[oi], 0,0,0);
        acc[oi] = __builtin_amdgcn_mfma_f32_16x16x32_bf16(ah, wl[oi][ks], acc[oi], 0,0,0);
        acc[oi] = __builtin_amdgcn_mfma_f32_16x16x32_bf16(al, wh[oi][ks], acc[oi], 0,0,0);
      }
    }
    #pragma unroll
    for (int oi=0;oi<4;oi++)
      #pragma unroll
      for (int r=0;r<4;r++) rmax[oi][r] = fmaxf(rmax[oi][r], acc[oi][r]);
    if (k+1 < KNB){
      #pragma unroll
      for (int e=0;e<16;e++) uc[e]=un[e];
    }
  }
  float xs[4] = {0.f,0.f,0.f,0.f};
  #pragma unroll
  for (int oi=0;oi<4;oi++){
    int o = oi*16 + r15;
    float bv = bf[o];
    #pragma unroll
    for (int r=0;r<4;r++){
      float y = lrelu(rmax[oi][r] + bv);
      size_t pg = ((size_t)b<<12) + p0 + w*16 + rb*4 + r;
      if (xout) xout[pg*64 + o] = y;
      Xb[pg*192 + coff + o] = pack2(y);
      xs[r] += y*y;
    }
  }
  if (xxout){
    #pragma unroll
    for (int r=0;r<4;r++){
      float s = xs[r];
      s += __shfl_xor(s,1); s += __shfl_xor(s,2); s += __shfl_xor(s,4); s += __shfl_xor(s,8);
      if (r15==0) xxout[((size_t)b<<12) + p0 + w*16 + rb*4 + r] = s;
    }
  }
}

// ---- edge block 3: x3[n] = lrelu(V5[n] + max_k U5[m_k]) -- pure gather+max ----
__global__ __launch_bounds__(256) void k_ec3(const float* __restrict__ Ut, const float* __restrict__ Vt,
    const int* __restrict__ idx, unsigned* __restrict__ Xb){
  int wid = threadIdx.x>>6, lane = threadIdx.x&63;
  int pt = blockIdx.x*4 + wid, b = pt>>12, n = pt&4095;
  const float* Ub = Ut + (((size_t)b)<<12)*64;
  int mr[KNB];
  const int4* ip4 = (const int4*)(idx + (size_t)pt*KNB);
  #pragma unroll
  for (int q=0;q<5;q++){ int4 t = ip4[q]; mr[q*4+0]=t.x; mr[q*4+1]=t.y; mr[q*4+2]=t.z; mr[q*4+3]=t.w; }
  float mx = -INFINITY;
  #pragma unroll
  for (int k=0;k<KNB;k++) mx = fmaxf(mx, Ub[(size_t)mr[k]*64 + lane]);
  mx = lrelu(mx + Vt[(size_t)pt*64 + lane]);
  Xb[((size_t)((b<<12)+n))*192 + 128 + lane] = pack2(mx);
}

// ---- KNN distance via split-bf16 MFMA: pd = fenc(fma(2,dot,-xx_n) - xx_m) ----
// Emits per-(row, 64-col-chunk) max via shfl reduce.
__global__ __launch_bounds__(512) void k_knn_mfma(const unsigned* __restrict__ Xp, int coff,
        const float* __restrict__ xx, unsigned* __restrict__ pd, unsigned* __restrict__ cmax,
        int q0, int S){
  __shared__ short Ah[128][40];
  __shared__ short Al[128][40];
  __shared__ short Bh[128][40];
  __shared__ short Bl[128][40];
  int tid = threadIdx.x;
  int bx = blockIdx.x, by = blockIdx.y, bz = blockIdx.z;
  int w = tid>>6, lane = tid&63;
  int r15 = lane&15, rb = lane>>4;
  int mibase = (w&3)*32, oibase = (w>>2)*64;
  f32x4 acc[2][4];
  #pragma unroll
  for (int mi=0;mi<2;mi++)
    #pragma unroll
    for (int oi=0;oi<4;oi++) acc[mi][oi] = (f32x4){0.f,0.f,0.f,0.f};
  int srow = tid>>2, sc = (tid&3)*8;
  const unsigned* pa = Xp + ((size_t)((bz<<12) + q0 + by*128 + srow))*192 + coff + sc;
  const unsigned* pb = Xp + ((size_t)((bz<<12) + bx*128 + srow))*192 + coff + sc;
  for (int kt=0; kt<64; kt+=32){
    if (kt) __syncthreads();
    uint4 a0 = *(const uint4*)(pa+kt);
    uint4 a1 = *(const uint4*)(pa+kt+4);
    uint4 b0 = *(const uint4*)(pb+kt);
    uint4 b1 = *(const uint4*)(pb+kt+4);
    short8v h, l;
    cvt8(a0,a1,h,l);
    *(short8v*)&Ah[srow][sc] = h; *(short8v*)&Al[srow][sc] = l;
    cvt8(b0,b1,h,l);
    *(short8v*)&Bh[srow][sc] = h; *(short8v*)&Bl[srow][sc] = l;
    __syncthreads();
    short8v ah[2], al[2];
    #pragma unroll
    for (int mi=0;mi<2;mi++){
      ah[mi] = *(const short8v*)&Ah[mibase+mi*16+r15][rb*8];
      al[mi] = *(const short8v*)&Al[mibase+mi*16+r15][rb*8];
    }
    #pragma unroll
    for (int oi=0;oi<4;oi++){
      short8v bh = *(const short8v*)&Bh[oibase+oi*16+r15][rb*8];
      short8v bl = *(const short8v*)&Bl[oibase+oi*16+r15][rb*8];
      #pragma unroll
      for (int mi=0;mi<2;mi++){
        acc[mi][oi] = __builtin_amdgcn_mfma_f32_16x16x32_bf16(ah[mi], bh, acc[mi][oi], 0,0,0);
        acc[mi][oi] = __builtin_amdgcn_mfma_f32_16x16x32_bf16(ah[mi], bl, acc[mi][oi], 0,0,0);
        acc[mi][oi] = __builtin_amdgcn_mfma_f32_16x16x32_bf16(al[mi], bh, acc[mi][oi], 0,0,0);
      }
    }
  }
  float xm[4];
  #pragma unroll
  for (int oi=0;oi<4;oi++) xm[oi] = xx[(bz<<12) + bx*128 + oibase + oi*16 + r15];
  #pragma unroll
  for (int mi=0;mi<2;mi++){
    #pragma unroll
    for (int r=0;r<4;r++){
      int row = by*128 + mibase + mi*16 + rb*4 + r;
      float xn = xx[(bz<<12) + q0 + row];
      float f0 = fmaf(2.f, acc[mi][0][r], -xn) - xm[0];
      float f1 = fmaf(2.f, acc[mi][1][r], -xn) - xm[1];
      float f2 = fmaf(2.f, acc[mi][2][r], -xn) - xm[2];
      float f3 = fmaf(2.f, acc[mi][3][r], -xn) - xm[3];
      unsigned* dst = pd + ((size_t)(bz*S + row))*N_PTS + bx*128 + oibase;
      dst[ 0+r15] = fenc(f0);
      dst[16+r15] = fenc(f1);
      dst[32+r15] = fenc(f2);
      dst[48+r15] = fenc(f3);
      float m = fmaxf(fmaxf(f0,f1), fmaxf(f2,f3));
      m = fmaxf(m, __shfl_xor(m,1));
      m = fmaxf(m, __shfl_xor(m,2));
      m = fmaxf(m, __shfl_xor(m,4));
      m = fmaxf(m, __shfl_xor(m,8));
      if (r15 == 0)
        cmax[((size_t)(bz<<12) + q0 + row)*64 + bx*2 + (oibase>>6)] = fenc(m);
    }
  }
}

__device__ __forceinline__ unsigned bitsort_u32(unsigned v, int lane){
  #pragma unroll
  for (int k=2;k<=64;k<<=1){
    #pragma unroll
    for (int j=k>>1;j>0;j>>=1){
      unsigned o = (unsigned)__shfl_xor((int)v, j);
      bool takeMax = (((lane & j) != 0) == ((lane & k) == 0));
      unsigned mx = v>o?v:o, mn = v<o?v:o;
      v = takeMax ? mx : mn;
    }
  }
  return v;   // ascending by lane
}

// ---- filtered top-20: chunk-max prefilter + streaming candidate selection ----
__global__ __launch_bounds__(256,6) void k_topk20(const unsigned* __restrict__ pdbuf,
        const unsigned* __restrict__ cmax, int* __restrict__ idxout, int q0, int sshift){
  __shared__ unsigned long long cand[4][64];
  int wid = threadIdx.x>>6, lane = threadIdx.x&63;
  int gw = blockIdx.x*4 + wid;
  int S = 1 << sshift;
  int b = gw >> sshift, i = gw & (S-1);
  const unsigned* row = pdbuf + ((size_t)b*S + i)*N_PTS;
  unsigned cm = cmax[((size_t)b*N_PTS + q0 + i)*64 + lane];
  unsigned T = (unsigned)__shfl((int)bitsort_u32(cm, lane), 44);
  unsigned long long qual = __ballot(cm >= T);
  unsigned lmax = 0u;
  for (int c=0;c<64;c++){
    if (!((qual>>c)&1ull)) continue;
    unsigned vv = row[c*64 + lane];
    lmax = lmax > vv ? lmax : vv;
  }
  unsigned T2 = (unsigned)__shfl((int)bitsort_u32(lmax, lane), 44);
  int base = 0;
  unsigned long long below = (1ull<<lane) - 1ull;
  for (int c=0;c<64;c++){
    if (!((qual>>c)&1ull)) continue;
    unsigned vv = row[c*64 + lane];
    bool isc = vv >= T2;
    unsigned long long mb = __ballot(isc);
    int pos = base + __popcll(mb & below);
    if (isc && pos < 64){
      int m = c*64 + lane;
      cand[wid][pos] = (((unsigned long long)vv)<<12) | (unsigned)(4095-m);
    }
    base += __popcll(mb);
  }
  unsigned long long K;
  if (base <= 64){
    unsigned long long kv = (lane < base) ? cand[wid][lane] : 0ull;
    #pragma unroll
    for (int k=2;k<=64;k<<=1){
      #pragma unroll
      for (int j=k>>1;j>0;j>>=1){
        unsigned long long o = __shfl_xor(kv, j);
        bool takeMax = (((lane & j) != 0) == ((lane & k) == 0));
        unsigned long long mx = kv>o?kv:o, mn = kv<o?kv:o;
        kv = takeMax ? mx : mn;
      }
    }
    K = __shfl(kv, 44);
  } else {
    K = 0ull;
    for (int bb2=43; bb2>=0; --bb2){
      unsigned long long cnd = K | (1ull<<bb2);
      int lc = 0;
      for (int c=0;c<64;c++){
        if (!((qual>>c)&1ull)) continue;
        unsigned vv = row[c*64 + lane];
        int m = c*64 + lane;
        unsigned long long key = (((unsigned long long)vv)<<12) | (unsigned)(4095-m);
        if (key >= cnd) lc++;
      }
      #pragma unroll
      for (int off=32; off; off>>=1) lc += __shfl_xor(lc, off);
      if (lc >= KNB) K = cnd;
    }
  }
  int eb = 0;
  int* dst = idxout + ((size_t)b*N_PTS + (q0+i))*KNB;
  for (int c=0;c<64;c++){
    if (!((qual>>c)&1ull)) continue;
    unsigned vv = row[c*64 + lane];
    int m = c*64 + lane;
    unsigned long long key = (((unsigned long long)vv)<<12) | (unsigned)(4095-m);
    bool sel = key >= K;
    unsigned long long mb = __ballot(sel);
    int pos = eb + __popcll(mb & below);
    if (sel) dst[pos] = m;
    eb += __popcll(mb);
  }
}

// ---- split-bf16 MFMA GEMM ----
// STORE: 0 = column-max only (gmax), 1 = packed u32 store [pt][ldo], 2 = f32 store to d_out (O=13)
template<int STORE, int RELU>
__global__ __launch_bounds__(512) void k_mgemm(const unsigned* __restrict__ Ap, int lda,
        const unsigned* __restrict__ Bp, int ldb,
        const float* __restrict__ bias, int perBatch,
        unsigned* __restrict__ Cp, int ldo, float* __restrict__ Cf,
        unsigned* __restrict__ gmax, int O, int K){
  __shared__ short Ah[128][40];
  __shared__ short Al[128][40];
  __shared__ short Bh[128][40];
  __shared__ short Bl[128][40];
  int tid = threadIdx.x;
  int bx = blockIdx.x, by = blockIdx.y, bz = blockIdx.z;
  int w = tid>>6, lane = tid&63;
  int r15 = lane&15, rb = lane>>4;
  int mibase = (w&3)*32, oibase = (w>>2)*64;
  f32x4 acc[2][4];
  #pragma unroll
  for (int mi=0;mi<2;mi++)
    #pragma unroll
    for (int oi=0;oi<4;oi++) acc[mi][oi] = (f32x4){0.f,0.f,0.f,0.f};
  int srow = tid>>2, sc = (tid&3)*8;
  const unsigned* pa = Ap + ((size_t)((bz<<12) + bx*128 + srow))*lda + sc;
  const unsigned* pb = Bp + (size_t)(by*128 + srow)*ldb + sc;
  for (int kt=0; kt<K; kt+=32){
    if (kt) __syncthreads();
    uint4 a0 = *(const uint4*)(pa+kt);
    uint4 a1 = *(const uint4*)(pa+kt+4);
    uint4 b0 = *(const uint4*)(pb+kt);
    uint4 b1 = *(const uint4*)(pb+kt+4);
    short8v h, l;
    cvt8(a0,a1,h,l);
    *(short8v*)&Ah[srow][sc] = h; *(short8v*)&Al[srow][sc] = l;
    cvt8(b0,b1,h,l);
    *(short8v*)&Bh[srow][sc] = h; *(short8v*)&Bl[srow][sc] = l;
    __syncthreads();
    short8v ah[2], al[2];
    #pragma unroll
    for (int mi=0;mi<2;mi++){
      ah[mi] = *(const short8v*)&Ah[mibase+mi*16+r15][rb*8];
      al[mi] = *(const short8v*)&Al[mibase+mi*16+r15][rb*8];
    }
    #pragma unroll
    for (int oi=0;oi<4;oi++){
      short8v bh = *(const short8v*)&Bh[oibase+oi*16+r15][rb*8];
      short8v bl = *(const short8v*)&Bl[oibase+oi*16+r15][rb*8];
      #pragma unroll
      for (int mi=0;mi<2;mi++){
        acc[mi][oi] = __builtin_amdgcn_mfma_f32_16x16x32_bf16(ah[mi], bh, acc[mi][oi], 0,0,0);
        acc[mi][oi] = __builtin_amdgcn_mfma_f32_16x16x32_bf16(ah[mi], bl, acc[mi][oi], 0,0,0);
        acc[mi][oi] = __builtin_amdgcn_mfma_f32_16x16x32_bf16(al[mi], bh, acc[mi][oi], 0,0,0);
      }
    }
  }
  #pragma unroll
  for (int oi=0;oi<4;oi++){
    int o = by*128 + oibase + oi*16 + r15;
    float bv = 0.f;
    if (bias != nullptr) bv = perBatch ? bias[bz*O + o] : bias[o];
    float cmx = -INFINITY;
    #pragma unroll
    for (int mi=0;mi<2;mi++){
      #pragma unroll
      for (int r=0;r<4;r++){
        float y = acc[mi][oi][r] + bv;
        if (RELU) y = lrelu(y);
        if (STORE==1){
          int pt = bx*128 + mibase + mi*16 + rb*4 + r;
          Cp[((size_t)((bz<<12)+pt))*ldo + o] = pack2(y);
        } else if (STORE==2){
          if (o < 13){
            int pt = bx*128 + mibase + mi*16 + rb*4 + r;
            Cf[(((size_t)(bz*13 + o))<<12) + pt] = y;
          }
        } else {
          cmx = fmaxf(cmx, y);
        }
      }
    }
    if (STORE==0){
      cmx = fmaxf(cmx, __shfl_xor(cmx,16));
      cmx = fmaxf(cmx, __shfl_xor(cmx,32));
      if (rb==0) atomicMax(&gmax[bz*1024 + o], fenc(cmx));
    }
  }
}

// bias7[b][o] = sum_{c<1024} Wf7[o][c]*g[b][c] + bf7[o]
__global__ __launch_bounds__(256) void k_gemv7(const float* __restrict__ Wf7, const float* __restrict__ bf7,
                        const unsigned* __restrict__ g, float* __restrict__ bias7){
  int wid = threadIdx.x>>6, lane = threadIdx.x&63;
  int o = blockIdx.x*4 + wid, b = blockIdx.y;
  const float* wr = Wf7 + (size_t)o*1216;
  const unsigned* gb = g + b*1024;
  float acc = 0.f;
  for (int c = lane; c < 1024; c += 64)
    acc = fmaf(wr[c], fdec(gb[c]), acc);
  #pragma unroll
  for (int off=32; off; off>>=1) acc += __shfl_xor(acc, off);
  if (lane==0) bias7[b*512+o] = acc + bf7[o];
}

extern "C" void kernel_launch(void* const* d_in, const int* in_sizes, int n_in,
                              void* d_out, int out_size, void* d_ws, size_t ws_size,
                              hipStream_t stream){
  const float* x  = (const float*)d_in[0];
  const float* W1 = (const float*)d_in[1];
  const float* W2 = (const float*)d_in[2];
  const float* W3 = (const float*)d_in[3];
  const float* W4 = (const float*)d_in[4];
  const float* W5 = (const float*)d_in[5];
  const float* W6 = (const float*)d_in[6];
  const float* W7 = (const float*)d_in[7];
  const float* W8 = (const float*)d_in[8];
  const float* W9 = (const float*)d_in[9];
  const float* bn1 = (const float*)d_in[10];
  const float* bn2 = (const float*)d_in[11];
  const float* bn3 = (const float*)d_in[12];
  const float* bn4 = (const float*)d_in[13];
  const float* bn5 = (const float*)d_in[14];
  const float* bn6 = (const float*)d_in[15];
  const float* bn7 = (const float*)d_in[16];
  const float* bn8 = (const float*)d_in[17];

  float* ws = (float*)d_ws;
  size_t off = 0;
  auto alloc = [&](size_t nf){ float* p = ws + off; off += (nf + 63) & ~(size_t)63; return p; };
  float* Wf7 = alloc((size_t)512*1216); float* bf7 = alloc(512);
  float* bf6 = alloc(1024);
  float* bf8 = alloc(256);
  float* bf2 = alloc(64);
  float* bf4 = alloc(64);
  unsigned* Wb2p = (unsigned*)alloc((size_t)64*64);
  unsigned* Wb4p = (unsigned*)alloc((size_t)64*64);
  unsigned* Wb6p = (unsigned*)alloc((size_t)1024*192);
  unsigned* Wb7p = (unsigned*)alloc((size_t)512*192);
  unsigned* Wb8p = (unsigned*)alloc((size_t)256*512);
  unsigned* Wb9p = (unsigned*)alloc((size_t)128*256);
  float* W3LT4 = alloc(64*64);    float* W3RdT4 = alloc(64*64); float* bf3 = alloc(64);
  float* W5LT4 = alloc(64*64);    float* W5RdT4 = alloc(64*64); float* bf5 = alloc(64);
  float* U1  = alloc(4*KNB*64);
  float* V1  = alloc((size_t)4*N_PTS*64);
  float* x1t = alloc((size_t)4*N_PTS*64);
  float* x2t = alloc((size_t)4*N_PTS*64);
  float* Ut3 = alloc((size_t)4*N_PTS*64);
  float* Vt3 = alloc((size_t)4*N_PTS*64);
  float* Ut5 = alloc((size_t)4*N_PTS*64);
  float* Vt5 = alloc((size_t)4*N_PTS*64);
  unsigned* Xb = (unsigned*)alloc((size_t)4*N_PTS*192);   // packed activations [n][192]
  float* xx1 = alloc(4*N_PTS);
  float* xx2 = alloc(4*N_PTS);
  int* idx1 = (int*)alloc((size_t)4*N_PTS*KNB);
  int* idx2 = (int*)alloc((size_t)4*N_PTS*KNB);
  unsigned* genc = (unsigned*)alloc(4*1024);
  float* bias7 = alloc(4*512);
  unsigned* h8p = (unsigned*)alloc((size_t)4*N_PTS*256);  // packed conv8 out [n][256]
  unsigned* cmaxb = (unsigned*)alloc((size_t)4*N_PTS*64);
  // pdbuf stripe: cap at S=1024 (64 MB, L3-resident sweet spot)
  size_t remaining = (ws_size / 4 > off) ? (ws_size / 4 - off) : 0;
  int S = 4096;
  while (S > 512 && (size_t)4*S*N_PTS + 1024 > remaining) S >>= 1;
  if (S > 1024) S = 1024;
  int sshift = 31 - __builtin_clz(S);
  unsigned* pdbuf = (unsigned*)alloc((size_t)4*S*N_PTS);   // encoded u32; reused as h7p (needs 32MB)
  unsigned* h7p = pdbuf;                                    // packed conv7 out [n][512]

  // single merged prep kernel (14 independent sub-tasks, block-range dispatch)
  k_prep<<<8452,256,0,stream>>>(x, W1, W2, W3, W4, W5, W6, W7, W8, W9,
                                bn1, bn2, bn3, bn4, bn5, bn6, bn7, bn8,
                                Wf7, bf7, Wb2p, bf2, Wb4p, bf4, Wb6p, bf6, Wb7p,
                                Wb8p, bf8, Wb9p, W3LT4, bf3, W3RdT4, W5LT4, bf5, W5RdT4,
                                U1, V1, genc);

  // edge block 1: MFMA edge-conv (neighbors = points 0..19, U1 indexed by k)
  k_edgemm<0><<<dim3(64,1,4),256,0,stream>>>(U1, V1, nullptr, Wb2p, bf2, x1t, Xb, 0, xx1);

  int nstripe = N_PTS / S;
  // KNN on x1 (packed cols 0..63 of Xb)
  for (int s=0;s<nstripe;s++){
    k_knn_mfma<<<dim3(32,S/128,4),512,0,stream>>>(Xb, 0, xx1, pdbuf, cmaxb, s*S, S);
    k_topk20<<<S,256,0,stream>>>(pdbuf, cmaxb, idx1, s*S, sshift);
  }

  // edge block 2: U3/V3 then MFMA edge-conv with gather
  k_uv<<<4096,256,0,stream>>>(x1t, W3LT4, W3RdT4, bf3, Ut3, Vt3);
  k_edgemm<1><<<dim3(64,1,4),256,0,stream>>>(Ut3, Vt3, idx1, Wb4p, bf4, x2t, Xb, 64, xx2);

  // KNN on x2 (packed cols 64..127 of Xb)
  for (int s=0;s<nstripe;s++){
    k_knn_mfma<<<dim3(32,S/128,4),512,0,stream>>>(Xb, 64, xx2, pdbuf, cmaxb, s*S, S);
    k_topk20<<<S,256,0,stream>>>(pdbuf, cmaxb, idx2, s*S, sshift);
  }

  // edge block 3: U5/V5 then pure gather+max
  k_uv<<<4096,256,0,stream>>>(x2t, W5LT4, W5RdT4, bf5, Ut5, Vt5);
  k_ec3<<<4096,256,0,stream>>>(Ut5, Vt5, idx2, Xb);

  // conv6 (1024x192) -> only column max g (MFMA, gmax atomic)
  k_mgemm<0,1><<<dim3(32,8,4),512,0,stream>>>(Xb, 192, Wb6p, 192, bf6, 0, nullptr, 0, nullptr, genc, 1024, 192);
  // bias7[b][o] = W7[:, :1024] @ g + bf7
  k_gemv7<<<dim3(128,4),256,0,stream>>>(Wf7, bf7, genc, bias7);
  // conv7: W7[:, 1024:1216] @ X + bias7 (per batch) -> packed h7
  k_mgemm<1,1><<<dim3(32,4,4),512,0,stream>>>(Xb, 192, Wb7p, 192, bias7, 1, h7p, 512, nullptr, nullptr, 512, 192);
  // conv8: 256x512 -> packed h8
  k_mgemm<1,1><<<dim3(32,2,4),512,0,stream>>>(h7p, 512, Wb8p, 512, bf8, 0, h8p, 256, nullptr, nullptr, 256, 512);
  // conv9: 13x256 (padded to 128), no bias/relu -> d_out f32
  k_mgemm<2,0><<<dim3(32,1,4),512,0,stream>>>(h8p, 256, Wb9p, 256, nullptr, 0, nullptr, 0, (float*)d_out, nullptr, 13, 256);
}